// Round 1
// baseline (107.025 us; speedup 1.0000x reference)
//
#include <hip/hip_runtime.h>
#include <math.h>

// TripletLoss semi-hard mining, N=512, D=512.
// Reduced form of the reference: for each ordered positive pair (j,a):
//   neg = min over {k: label!=label[j], d[j][k] > d[j][a]} of d[j][k]
//         else max over negatives (0 if none)
//   loss += max(0, MARGIN + d[j][a] - neg);  out = loss / (numpos + 1e-8)

#define NN 512
#define DD 512
#define JT 2          // anchor rows per block
#define MARGIN_F 0.2f

__global__ __launch_bounds__(256) void triplet_main(
    const int* __restrict__ labels,
    const float* __restrict__ emb,
    float* __restrict__ loss_sum,
    unsigned int* __restrict__ pos_count)
{
    __shared__ float ej[JT * DD];            // anchor embeddings
    __shared__ float dist[JT][NN];           // distance rows
    __shared__ int slbl[NN];
    __shared__ unsigned short plist[JT][NN]; // positive indices per row
    __shared__ int pcnt[JT];

    const int tid = threadIdx.x;
    const int j0 = blockIdx.x * JT;

    // stage labels + anchor rows
    slbl[tid] = labels[tid];
    slbl[tid + 256] = labels[tid + 256];
    {
        const float4* src = (const float4*)(emb + (size_t)j0 * DD);
        ((float4*)ej)[tid] = src[tid];       // JT*DD/4 == 256, one float4/thread
    }
    if (tid < JT) pcnt[tid] = 0;
    __syncthreads();

    // ---- phase 1: distance rows (direct squared-difference, fp32) ----
    #pragma unroll
    for (int kk = 0; kk < NN; kk += 256) {
        const int k = kk + tid;
        const float4* ek = (const float4*)(emb + (size_t)k * DD);
        float acc0 = 0.f, acc1 = 0.f;
        #pragma unroll 4
        for (int d4 = 0; d4 < DD / 4; ++d4) {
            float4 e = ek[d4];
            float4 a0 = ((const float4*)ej)[d4];          // wave-uniform (broadcast)
            float4 a1 = ((const float4*)(ej + DD))[d4];
            float t;
            t = a0.x - e.x; acc0 = fmaf(t, t, acc0);
            t = a0.y - e.y; acc0 = fmaf(t, t, acc0);
            t = a0.z - e.z; acc0 = fmaf(t, t, acc0);
            t = a0.w - e.w; acc0 = fmaf(t, t, acc0);
            t = a1.x - e.x; acc1 = fmaf(t, t, acc1);
            t = a1.y - e.y; acc1 = fmaf(t, t, acc1);
            t = a1.z - e.z; acc1 = fmaf(t, t, acc1);
            t = a1.w - e.w; acc1 = fmaf(t, t, acc1);
        }
        dist[0][k] = (k == j0)     ? 0.f : sqrtf(acc0);   // exact-0 diagonal
        dist[1][k] = (k == j0 + 1) ? 0.f : sqrtf(acc1);
    }
    __syncthreads();

    // ---- phase 2a: build positive lists ----
    #pragma unroll
    for (int r = 0; r < JT; ++r) {
        const int j = j0 + r;
        const int lbl = slbl[j];
        for (int aa = tid; aa < NN; aa += 256) {
            if (aa != j && slbl[aa] == lbl) {
                int idx = atomicAdd(&pcnt[r], 1);
                plist[r][idx] = (unsigned short)aa;
            }
        }
    }
    __syncthreads();

    // ---- phase 2b: one wave per positive pair, shuffle reductions ----
    const int wave = tid >> 6;
    const int lane = tid & 63;
    float wave_loss = 0.f;

    for (int r = 0; r < JT; ++r) {
        const int j = j0 + r;
        const int lbl = slbl[j];
        const int np = pcnt[r];
        for (int p = wave; p < np; p += 4) {
            const int a = plist[r][p];
            const float dpa = dist[r][a];
            float vmin = 1e30f;   // min negative strictly farther than dpa
            float vmax = 0.f;     // max negative (fallback; 0 if no negatives)
            #pragma unroll
            for (int i = 0; i < NN / 64; ++i) {
                const int k = lane + i * 64;
                const float dk = dist[r][k];
                if (slbl[k] != lbl) {
                    vmax = fmaxf(vmax, dk);
                    if (dk > dpa) vmin = fminf(vmin, dk);
                }
            }
            #pragma unroll
            for (int o = 32; o > 0; o >>= 1) {
                vmin = fminf(vmin, __shfl_xor(vmin, o, 64));
                vmax = fmaxf(vmax, __shfl_xor(vmax, o, 64));
            }
            const float negd = (vmin < 1e29f) ? vmin : vmax;
            const float term = MARGIN_F + dpa - negd;
            if (lane == 0 && term > 0.f) wave_loss += term;
        }
        (void)j;
    }
    if (lane == 0 && wave_loss != 0.f) atomicAdd(loss_sum, wave_loss);
    if (tid == 0) {
        int c = 0;
        #pragma unroll
        for (int r = 0; r < JT; ++r) c += pcnt[r];
        atomicAdd(pos_count, (unsigned int)c);
    }
}

__global__ void triplet_finalize(const float* __restrict__ loss_sum,
                                 const unsigned int* __restrict__ pos_count,
                                 float* __restrict__ out)
{
    out[0] = loss_sum[0] / ((float)pos_count[0] + 1e-8f);
}

extern "C" void kernel_launch(void* const* d_in, const int* in_sizes, int n_in,
                              void* d_out, int out_size, void* d_ws, size_t ws_size,
                              hipStream_t stream) {
    const int* labels = (const int*)d_in[0];
    const float* emb  = (const float*)d_in[1];
    float* loss_sum = (float*)d_ws;
    unsigned int* cnt = (unsigned int*)((char*)d_ws + sizeof(float));

    hipMemsetAsync(d_ws, 0, 2 * sizeof(float), stream);
    triplet_main<<<NN / JT, 256, 0, stream>>>(labels, emb, loss_sum, cnt);
    triplet_finalize<<<1, 1, 0, stream>>>(loss_sum, cnt, (float*)d_out);
}

// Round 2
// 83.567 us; speedup vs baseline: 1.2807x; 1.2807x over previous
//
#include <hip/hip_runtime.h>
#include <math.h>

// TripletLoss semi-hard mining, N=512, D=512, C=64.
// For each ordered positive pair (j,a) [labels equal, j!=a]:
//   neg = min{ d[j][k] : lbl[k]!=lbl[j], d[j][k] > d[j][a] }
//         else max{ d[j][k] : lbl[k]!=lbl[j] } (0 if none)
//   loss += max(0, MARGIN + d[j][a] - neg);  out = loss / (numpos + 1e-8)
// d2 via Gram form (matches reference): d2[j][k] = s[j] + s[k] - 2*dot(e_j,e_k)

#define NN 512
#define DD 512
#define JT 2                  // anchor rows per block
#define TPB 512               // 8 waves; thread t owns k-row t
#define NWAVES (TPB / 64)
#define DC 64                 // d-chunk staged per iteration
#define NCHUNK (DD / DC)      // 8
#define LSTR (DC + 4)         // padded LDS row stride (floats); keeps b128 alignment
#define NF4 (DC / 4)          // 16 float4 per row-chunk
#define MARGIN_F 0.2f

__global__ __launch_bounds__(TPB) void triplet_main(
    const int* __restrict__ labels,
    const float* __restrict__ emb,
    float* __restrict__ part_loss,
    int* __restrict__ part_cnt)
{
    __shared__ float bch[NN * LSTR];          // 512*68*4 = 139264 B staging buffer
    __shared__ float dist[JT][NN];
    __shared__ int slbl[NN];
    __shared__ unsigned short plist[JT][NN];
    __shared__ int pcnt[JT];
    __shared__ float snorm[JT];
    __shared__ float bloss;

    const int tid = threadIdx.x;
    const int j0 = blockIdx.x * JT;

    slbl[tid] = labels[tid];
    if (tid < JT) pcnt[tid] = 0;
    if (tid == 0) bloss = 0.f;

    float g0 = 0.f, g1 = 0.f, ss = 0.f;       // dot(a0,row), dot(a1,row), dot(row,row)

    for (int c = 0; c < NCHUNK; ++c) {
        __syncthreads();                      // prior chunk's readers done
        // ---- coalesced global -> LDS staging: [512 rows][DC floats] ----
        #pragma unroll
        for (int u = 0; u < (NN * NF4) / TPB; ++u) {     // 16 float4 per thread
            const int idx = tid + u * TPB;               // 0..8191
            const int r  = idx >> 4;                     // 16 f4 per row
            const int c4 = idx & 15;
            float4 v = *(const float4*)(emb + (size_t)r * DD + c * DC + (c4 << 2));
            *(float4*)(&bch[r * LSTR + (c4 << 2)]) = v;  // 16B aligned (LSTR=68)
        }
        __syncthreads();
        // ---- compute: thread t consumes its own row chunk ----
        const float4* own = (const float4*)(&bch[tid * LSTR]);
        const float4* a0p = (const float4*)(&bch[j0 * LSTR]);        // broadcast
        const float4* a1p = (const float4*)(&bch[(j0 + 1) * LSTR]);  // broadcast
        #pragma unroll 8
        for (int i = 0; i < NF4; ++i) {
            const float4 x  = own[i];
            const float4 a0 = a0p[i];
            const float4 a1 = a1p[i];
            g0 = fmaf(a0.x, x.x, g0); g0 = fmaf(a0.y, x.y, g0);
            g0 = fmaf(a0.z, x.z, g0); g0 = fmaf(a0.w, x.w, g0);
            g1 = fmaf(a1.x, x.x, g1); g1 = fmaf(a1.y, x.y, g1);
            g1 = fmaf(a1.z, x.z, g1); g1 = fmaf(a1.w, x.w, g1);
            ss = fmaf(x.x, x.x, ss);  ss = fmaf(x.y, x.y, ss);
            ss = fmaf(x.z, x.z, ss);  ss = fmaf(x.w, x.w, ss);
        }
    }

    // share anchor self-norms (thread j0/j0+1 own those rows; g==ss there bitwise,
    // so the diagonal d2 is exactly 0, matching the reference zero-mask path)
    if (tid == j0)     snorm[0] = ss;
    if (tid == j0 + 1) snorm[1] = ss;
    __syncthreads();
    {
        const float s0 = snorm[0], s1 = snorm[1];
        const float d20 = fmaxf(s0 + ss - 2.f * g0, 0.f);
        const float d21 = fmaxf(s1 + ss - 2.f * g1, 0.f);
        dist[0][tid] = sqrtf(d20);
        dist[1][tid] = sqrtf(d21);
    }
    __syncthreads();

    // ---- positive lists ----
    #pragma unroll
    for (int r = 0; r < JT; ++r) {
        const int j = j0 + r;
        if (tid != j && slbl[tid] == slbl[j]) {
            const int idx = atomicAdd(&pcnt[r], 1);
            plist[r][idx] = (unsigned short)tid;
        }
    }
    __syncthreads();

    // ---- mining: one wave per positive pair ----
    const int wave = tid >> 6;
    const int lane = tid & 63;
    float wloss = 0.f;
    for (int r = 0; r < JT; ++r) {
        const int lbl = slbl[j0 + r];
        const int np = pcnt[r];
        for (int p = wave; p < np; p += NWAVES) {
            const int a = plist[r][p];
            const float dpa = dist[r][a];
            float vmin = 1e30f;   // min negative strictly farther than dpa
            float vmax = 0.f;     // fallback: max negative (0 if none)
            #pragma unroll
            for (int i = 0; i < NN / 64; ++i) {
                const int k = lane + (i << 6);
                const float dk = dist[r][k];
                if (slbl[k] != lbl) {
                    vmax = fmaxf(vmax, dk);
                    if (dk > dpa) vmin = fminf(vmin, dk);
                }
            }
            #pragma unroll
            for (int o = 32; o > 0; o >>= 1) {
                vmin = fminf(vmin, __shfl_xor(vmin, o, 64));
                vmax = fmaxf(vmax, __shfl_xor(vmax, o, 64));
            }
            const float negd = (vmin < 1e29f) ? vmin : vmax;
            const float term = MARGIN_F + dpa - negd;
            if (lane == 0 && term > 0.f) wloss += term;
        }
    }
    if (lane == 0 && wloss != 0.f) atomicAdd(&bloss, wloss);
    __syncthreads();
    if (tid == 0) {
        part_loss[blockIdx.x] = bloss;                 // always written: no ws init needed
        part_cnt[blockIdx.x]  = pcnt[0] + pcnt[1];
    }
}

__global__ __launch_bounds__(256) void triplet_finalize(
    const float* __restrict__ part_loss,
    const int* __restrict__ part_cnt,
    float* __restrict__ out)
{
    __shared__ float sl[4];
    __shared__ int sc[4];
    const int tid = threadIdx.x;
    float L = part_loss[tid];
    int   c = part_cnt[tid];
    #pragma unroll
    for (int o = 32; o > 0; o >>= 1) {
        L += __shfl_xor(L, o, 64);
        c += __shfl_xor(c, o, 64);
    }
    if ((tid & 63) == 0) { sl[tid >> 6] = L; sc[tid >> 6] = c; }
    __syncthreads();
    if (tid == 0) {
        const float Ls = sl[0] + sl[1] + sl[2] + sl[3];
        const float cs = (float)(sc[0] + sc[1] + sc[2] + sc[3]);
        out[0] = Ls / (cs + 1e-8f);
    }
}

extern "C" void kernel_launch(void* const* d_in, const int* in_sizes, int n_in,
                              void* d_out, int out_size, void* d_ws, size_t ws_size,
                              hipStream_t stream) {
    const int* labels = (const int*)d_in[0];
    const float* emb  = (const float*)d_in[1];
    float* part_loss = (float*)d_ws;
    int*   part_cnt  = (int*)((char*)d_ws + (NN / JT) * sizeof(float));

    triplet_main<<<NN / JT, TPB, 0, stream>>>(labels, emb, part_loss, part_cnt);
    triplet_finalize<<<1, 256, 0, stream>>>(part_loss, part_cnt, (float*)d_out);
}